// Round 1
// baseline (160.281 us; speedup 1.0000x reference)
//
#include <hip/hip_runtime.h>
#include <math.h>

#define SRATE 16000
#define FRAME 320
#define LAGS 189
#define LAG_MIN 5
#define WIN_MED 30
#define BATCH 8
#define TLEN 80000
#define KFRAMES 250           // ceil(80000/320)
#define NOUT 235              // 250 + 14 - 30 + 1
#define NTOT (BATCH * NOUT)   // 1880
#define SEG (FRAME + LAGS)    // 509

// ---------------- Kernel 1: NCCF + per-frame best lag ----------------
__global__ __launch_bounds__(256) void nccf_best_kernel(
    const float* __restrict__ audio, int* __restrict__ best) {
  const int k = blockIdx.x;
  const int b = blockIdx.y;
  const float* row = audio + (size_t)b * TLEN;
  const int base = k * FRAME;

  __shared__ float sh[SEG];
  __shared__ float shv[LAGS];

  for (int j = threadIdx.x; j < SEG; j += blockDim.x) {
    int g = base + j;
    sh[j] = (g < TLEN) ? row[g] : 0.0f;   // zero-pad tail (last frame)
  }
  __syncthreads();

  const int l = threadIdx.x;
  if (l < LAGS) {
    float cross = 0.0f, e1 = 0.0f, e2 = 0.0f;
    const float* s2 = sh + l + 1;
    #pragma unroll 8
    for (int i = 0; i < FRAME; ++i) {
      float a = sh[i];
      float c = s2[i];
      cross += a * c;
      e1 += a * a;
      e2 += c * c;
    }
    float d1 = 1e-9f + sqrtf(e1);
    float d2 = 1e-9f + sqrtf(e2);
    shv[l] = cross / (d1 * d1) / (d2 * d2);
  }
  __syncthreads();

  if (threadIdx.x == 0) {
    // tail = nccf[LAG_MIN:], half = nccf[LAG_MIN : LAGS/2]
    float best_v = -INFINITY; int best_l = LAG_MIN;
    float half_v = -INFINITY; int half_l = LAG_MIN;
    for (int ll = LAG_MIN; ll < LAGS; ++ll) {
      float v = shv[ll];
      if (v > best_v) { best_v = v; best_l = ll; }   // strict > = first max
      if (ll < (LAGS / 2) && v > half_v) { half_v = v; half_l = ll; }
    }
    int chosen = (half_v > 0.99f * best_v) ? half_l : best_l;
    // returned idx = rel_argmax + LAG_MIN + 1 = (chosen - LAG_MIN) + LAG_MIN + 1
    best[b * KFRAMES + k] = chosen + 1;
  }
}

// ---------------- Kernel 2: frame energy (one wave per frame) ----------------
__global__ __launch_bounds__(256) void energy_kernel(
    const float* __restrict__ audio, float* __restrict__ out) {
  const int frame = blockIdx.x * 4 + (threadIdx.x >> 6);
  const int lane = threadIdx.x & 63;
  const int b = frame / KFRAMES;
  const int k = frame - b * KFRAMES;
  const float* row = audio + (size_t)b * TLEN + k * FRAME;
  float s = 0.0f;
  #pragma unroll
  for (int i = lane; i < FRAME; i += 64) {
    float v = row[i];
    s += v * v;
  }
  #pragma unroll
  for (int off = 32; off > 0; off >>= 1) s += __shfl_down(s, off, 64);
  if (lane == 0) out[3 * NTOT + frame] = s * (1.0f / FRAME);
}

// ---------------- Kernel 3: median smoothing + f0 + voiced + sums ----------------
__global__ __launch_bounds__(256) void median_f0_kernel(
    const int* __restrict__ best, float* __restrict__ out,
    double* __restrict__ acc) {
  const int b = blockIdx.x;
  __shared__ int sh_idx[KFRAMES];
  __shared__ double red[256];
  __shared__ double red2[256];

  for (int j = threadIdx.x; j < KFRAMES; j += blockDim.x)
    sh_idx[j] = best[b * KFRAMES + j];
  __syncthreads();

  const int t = threadIdx.x;
  double f0d = 0.0, f0sq = 0.0;
  if (t < NOUT) {
    int arr[WIN_MED];
    #pragma unroll
    for (int m = 0; m < WIN_MED; ++m) {
      int j = t + m - 14;          // left replicate-pad by 14
      if (j < 0) j = 0;
      arr[m] = sh_idx[j];
    }
    // 15th smallest (sorted index 14) via partial selection sort
    for (int s = 0; s <= 14; ++s) {
      int mi = s;
      for (int q = s + 1; q < WIN_MED; ++q)
        if (arr[q] < arr[mi]) mi = q;
      int tmp = arr[s]; arr[s] = arr[mi]; arr[mi] = tmp;
    }
    int med = arr[14];
    float f0 = 16000.0f / (1e-9f + (float)med);
    out[b * NOUT + t] = f0;                 // f0
    out[2 * NTOT + b * NOUT + t] = 1.0f;    // voiced (f0 > 0 always)
    f0d = (double)f0;
    f0sq = f0d * f0d;
  }
  red[t] = f0d;
  red2[t] = f0sq;
  __syncthreads();
  for (int s = 128; s > 0; s >>= 1) {
    if (t < s) { red[t] += red[t + s]; red2[t] += red2[t + s]; }
    __syncthreads();
  }
  if (t == 0) {
    atomicAdd(acc, red[0]);
    atomicAdd(acc + 1, red2[0]);
  }
}

// ---------------- Kernel 4: whiten ----------------
__global__ __launch_bounds__(256) void whiten_kernel(
    const double* __restrict__ acc, float* __restrict__ out) {
  const double n = (double)NTOT;
  double sum = acc[0], sumsq = acc[1];
  double mean = sum / n;
  double var = (sumsq - n * mean * mean) / (n - 1.0);
  if (var < 0.0) var = 0.0;
  double sd = sqrt(var);
  float fmean = (float)mean;
  float fsd = (sd == 0.0) ? 1.0f : (float)sd;
  int i = blockIdx.x * blockDim.x + threadIdx.x;
  if (i < NTOT) out[NTOT + i] = (out[i] - fmean) / fsd;
}

extern "C" void kernel_launch(void* const* d_in, const int* in_sizes, int n_in,
                              void* d_out, int out_size, void* d_ws, size_t ws_size,
                              hipStream_t stream) {
  const float* audio = (const float*)d_in[0];
  float* out = (float*)d_out;

  int* best = (int*)d_ws;                               // 2000 ints
  double* acc = (double*)((char*)d_ws + 8192);          // 2 doubles

  hipMemsetAsync(acc, 0, 2 * sizeof(double), stream);

  dim3 g1(KFRAMES, BATCH);
  nccf_best_kernel<<<g1, 256, 0, stream>>>(audio, best);
  energy_kernel<<<(BATCH * KFRAMES) / 4, 256, 0, stream>>>(audio, out);
  median_f0_kernel<<<BATCH, 256, 0, stream>>>(best, out, acc);
  whiten_kernel<<<(NTOT + 255) / 256, 256, 0, stream>>>(acc, out);
}

// Round 2
// 105.047 us; speedup vs baseline: 1.5258x; 1.5258x over previous
//
#include <hip/hip_runtime.h>
#include <math.h>

#define SRATE 16000
#define FRAME 320
#define LAGS 189
#define LAG_MIN 5
#define WIN_MED 30
#define BATCH 8
#define TLEN 80000
#define KFRAMES 250           // ceil(80000/320)
#define NOUT 235              // 250 + 14 - 30 + 1
#define NTOT (BATCH * NOUT)   // 1880
#define SEG (FRAME + LAGS)    // 509
#define CPY 516               // LDS copy stride (516 % 32 == 4 -> bank-quad offset)

// ---------------- Kernel 1: NCCF + per-frame best lag ----------------
// 4 shifted LDS copies so every lane can do aligned ds_read_b128 of its
// s2 window regardless of lag parity. copy r: shc[r][m] = seg[m + r].
__global__ __launch_bounds__(256) void nccf_best_kernel(
    const float* __restrict__ audio, int* __restrict__ best) {
  const int k = blockIdx.x;
  const int b = blockIdx.y;
  const float* row = audio + (size_t)b * TLEN;
  const int base = k * FRAME;

  __shared__ float sh[4 * CPY];   // 4 shifted copies, 512 floats each used
  __shared__ float shv[LAGS];

  for (int idx = threadIdx.x; idx < 4 * 512; idx += 256) {
    int r = idx >> 9;           // copy id 0..3
    int m = idx & 511;
    int srcj = m + r;           // seg index
    int g = base + srcj;
    float v = (srcj < SEG && g < TLEN) ? row[g] : 0.0f;
    sh[r * CPY + m] = v;
  }
  __syncthreads();

  const int l = threadIdx.x;
  if (l < LAGS) {
    const int lp1 = l + 1;
    const int r = lp1 & 3;
    const int s2base = r * CPY + (lp1 - r);   // float index; 16B-aligned
    float cross = 0.0f, e1 = 0.0f, e2 = 0.0f;
    #pragma unroll 4
    for (int i = 0; i < FRAME; i += 4) {
      float4 a = *(const float4*)&sh[i];            // broadcast (copy 0)
      float4 c = *(const float4*)&sh[s2base + i];   // per-lane b128
      cross += a.x * c.x + a.y * c.y + a.z * c.z + a.w * c.w;
      e1 += a.x * a.x + a.y * a.y + a.z * a.z + a.w * a.w;
      e2 += c.x * c.x + c.y * c.y + c.z * c.z + c.w * c.w;
    }
    float d1 = 1e-9f + sqrtf(e1);
    float d2 = 1e-9f + sqrtf(e2);
    shv[l] = cross / (d1 * d1) / (d2 * d2);
  }
  __syncthreads();

  if (threadIdx.x == 0) {
    float best_v = -INFINITY; int best_l = LAG_MIN;
    float half_v = -INFINITY; int half_l = LAG_MIN;
    for (int ll = LAG_MIN; ll < LAGS; ++ll) {
      float v = shv[ll];
      if (v > best_v) { best_v = v; best_l = ll; }     // strict > = first max
      if (ll < (LAGS / 2) && v > half_v) { half_v = v; half_l = ll; }
    }
    int chosen = (half_v > 0.99f * best_v) ? half_l : best_l;
    best[b * KFRAMES + k] = chosen + 1;
  }
}

// ---------------- Kernel 2: frame energy (one wave per frame) ----------------
__global__ __launch_bounds__(256) void energy_kernel(
    const float* __restrict__ audio, float* __restrict__ out) {
  const int frame = blockIdx.x * 4 + (threadIdx.x >> 6);
  const int lane = threadIdx.x & 63;
  const int b = frame / KFRAMES;
  const int k = frame - b * KFRAMES;
  const float* row = audio + (size_t)b * TLEN + k * FRAME;
  float s = 0.0f;
  #pragma unroll
  for (int i = lane; i < FRAME; i += 64) {
    float v = row[i];
    s += v * v;
  }
  #pragma unroll
  for (int off = 32; off > 0; off >>= 1) s += __shfl_down(s, off, 64);
  if (lane == 0) out[3 * NTOT + frame] = s * (1.0f / FRAME);
}

// ---------------- Kernel 3: median smoothing + f0 + voiced + sums ----------------
// Rank-count median: all private-array indexing is STATIC (fully unrolled)
// so arr[] stays in VGPRs — no scratch spill (R1's 79us lesson).
__global__ __launch_bounds__(256) void median_f0_kernel(
    const int* __restrict__ best, float* __restrict__ out,
    double* __restrict__ acc) {
  const int b = blockIdx.x;
  __shared__ int sh_idx[KFRAMES];
  __shared__ double red[256];
  __shared__ double red2[256];

  for (int j = threadIdx.x; j < KFRAMES; j += blockDim.x)
    sh_idx[j] = best[b * KFRAMES + j];
  __syncthreads();

  const int t = threadIdx.x;
  double f0d = 0.0, f0sq = 0.0;
  if (t < NOUT) {
    int arr[WIN_MED];
    #pragma unroll
    for (int m = 0; m < WIN_MED; ++m) {
      int j = t + m - 14;          // left replicate-pad by 14
      if (j < 0) j = 0;
      arr[m] = sh_idx[j];
    }
    // value at sorted index 14 (lower median of 30): the unique value v with
    // count(< v) <= 14 < count(<= v)
    int med = arr[0];
    #pragma unroll
    for (int i = 0; i < WIN_MED; ++i) {
      int c_lt = 0, c_le = 0;
      #pragma unroll
      for (int j = 0; j < WIN_MED; ++j) {
        c_lt += (arr[j] < arr[i]) ? 1 : 0;
        c_le += (arr[j] <= arr[i]) ? 1 : 0;
      }
      if (c_lt <= 14 && c_le > 14) med = arr[i];
    }
    float f0 = 16000.0f / (1e-9f + (float)med);
    out[b * NOUT + t] = f0;                 // f0
    out[2 * NTOT + b * NOUT + t] = 1.0f;    // voiced
    f0d = (double)f0;
    f0sq = f0d * f0d;
  }
  red[t] = f0d;
  red2[t] = f0sq;
  __syncthreads();
  for (int s = 128; s > 0; s >>= 1) {
    if (t < s) { red[t] += red[t + s]; red2[t] += red2[t + s]; }
    __syncthreads();
  }
  if (t == 0) {
    atomicAdd(acc, red[0]);
    atomicAdd(acc + 1, red2[0]);
  }
}

// ---------------- Kernel 4: whiten ----------------
__global__ __launch_bounds__(256) void whiten_kernel(
    const double* __restrict__ acc, float* __restrict__ out) {
  const double n = (double)NTOT;
  double sum = acc[0], sumsq = acc[1];
  double mean = sum / n;
  double var = (sumsq - n * mean * mean) / (n - 1.0);
  if (var < 0.0) var = 0.0;
  double sd = sqrt(var);
  float fmean = (float)mean;
  float fsd = (sd == 0.0) ? 1.0f : (float)sd;
  int i = blockIdx.x * blockDim.x + threadIdx.x;
  if (i < NTOT) out[NTOT + i] = (out[i] - fmean) / fsd;
}

extern "C" void kernel_launch(void* const* d_in, const int* in_sizes, int n_in,
                              void* d_out, int out_size, void* d_ws, size_t ws_size,
                              hipStream_t stream) {
  const float* audio = (const float*)d_in[0];
  float* out = (float*)d_out;

  int* best = (int*)d_ws;                               // 2000 ints
  double* acc = (double*)((char*)d_ws + 8192);          // 2 doubles

  hipMemsetAsync(acc, 0, 2 * sizeof(double), stream);

  dim3 g1(KFRAMES, BATCH);
  nccf_best_kernel<<<g1, 256, 0, stream>>>(audio, best);
  energy_kernel<<<(BATCH * KFRAMES) / 4, 256, 0, stream>>>(audio, out);
  median_f0_kernel<<<BATCH, 256, 0, stream>>>(best, out, acc);
  whiten_kernel<<<(NTOT + 255) / 256, 256, 0, stream>>>(acc, out);
}

// Round 3
// 86.137 us; speedup vs baseline: 1.8608x; 1.2195x over previous
//
#include <hip/hip_runtime.h>
#include <math.h>

#define SRATE 16000
#define FRAME 320
#define LAGS 189
#define LAG_MIN 5
#define WIN_MED 30
#define BATCH 8
#define TLEN 80000
#define KFRAMES 250           // ceil(80000/320)
#define NOUT 235              // 250 + 14 - 30 + 1
#define NTOT (BATCH * NOUT)   // 1880
#define SEG (FRAME + LAGS)    // 509

// ---------------- Kernel 1: NCCF + best lag + frame energy ----------------
// One wave per frame. Thread t in [0,48) computes 4 consecutive lags
// (ll = 4t+d) with an 8-float rolling register window: 2 ds_read_b128 per
// 4-sample step for 4 lags (vs 8 in R2). Windows start at 4t -> 16B aligned.
__global__ __launch_bounds__(64) void nccf_best_kernel(
    const float* __restrict__ audio, int* __restrict__ best,
    float* __restrict__ out) {
  const int k = blockIdx.x;
  const int b = blockIdx.y;
  const float* row = audio + (size_t)b * TLEN;
  const int base = k * FRAME;

  __shared__ float sh[512];     // seg[0..508], zero-padded to 512
  __shared__ float shv[LAGS];

  // stage 512 floats (values beyond SEG or TLEN are zero)
  for (int c = threadIdx.x; c < 128; c += 64) {       // 128 float4 chunks
    int j = 4 * c;
    float4 v;
    if (j + 3 < SEG && base + j + 3 < TLEN) {
      v = *(const float4*)(row + base + j);
    } else {
      v.x = (j + 0 < SEG && base + j + 0 < TLEN) ? row[base + j + 0] : 0.0f;
      v.y = (j + 1 < SEG && base + j + 1 < TLEN) ? row[base + j + 1] : 0.0f;
      v.z = (j + 2 < SEG && base + j + 2 < TLEN) ? row[base + j + 2] : 0.0f;
      v.w = (j + 3 < SEG && base + j + 3 < TLEN) ? row[base + j + 3] : 0.0f;
    }
    *(float4*)&sh[j] = v;
  }
  __syncthreads();

  const int t = threadIdx.x;
  if (t < 48) {
    float wv[8];
    *(float4*)&wv[0] = *(const float4*)&sh[4 * t];
    float cr[4] = {0.f, 0.f, 0.f, 0.f};
    float e2[4] = {0.f, 0.f, 0.f, 0.f};
    float e1 = 0.f;
    for (int i0 = 0; i0 < FRAME; i0 += 4) {
      float4 a = *(const float4*)&sh[i0];               // broadcast
      *(float4*)&wv[4] = *(const float4*)&sh[4 * t + i0 + 4];
      e1 += a.x * a.x + a.y * a.y + a.z * a.z + a.w * a.w;
      #pragma unroll
      for (int d = 0; d < 4; ++d) {
        float c0 = wv[d + 1], c1 = wv[d + 2], c2 = wv[d + 3], c3 = wv[d + 4];
        cr[d] += a.x * c0 + a.y * c1 + a.z * c2 + a.w * c3;
        e2[d] += c0 * c0 + c1 * c1 + c2 * c2 + c3 * c3;
      }
      wv[0] = wv[4]; wv[1] = wv[5]; wv[2] = wv[6]; wv[3] = wv[7];
    }
    float d1 = 1e-9f + sqrtf(e1);
    float inv1 = 1.0f / (d1 * d1);
    #pragma unroll
    for (int d = 0; d < 4; ++d) {
      int ll = 4 * t + d;
      if (ll < LAGS) {
        float d2 = 1e-9f + sqrtf(e2[d]);
        shv[ll] = cr[d] * inv1 / (d2 * d2);
      }
    }
    if (t == 0) out[3 * NTOT + b * KFRAMES + k] = e1 * (1.0f / FRAME);
  }
  __syncthreads();

  if (threadIdx.x == 0) {
    float best_v = -INFINITY; int best_l = LAG_MIN;
    float half_v = -INFINITY; int half_l = LAG_MIN;
    for (int ll = LAG_MIN; ll < LAGS; ++ll) {
      float v = shv[ll];
      if (v > best_v) { best_v = v; best_l = ll; }     // strict > = first max
      if (ll < (LAGS / 2) && v > half_v) { half_v = v; half_l = ll; }
    }
    int chosen = (half_v > 0.99f * best_v) ? half_l : best_l;
    best[b * KFRAMES + k] = chosen + 1;
  }
}

// ---------------- Kernel 2: median smoothing (one wave per output) ----------------
// Rank-14 select via shuffle broadcasts: no private arrays -> no scratch spill.
__global__ __launch_bounds__(256) void median_f0_kernel(
    const int* __restrict__ best, float* __restrict__ out) {
  const int w = blockIdx.x * 4 + (threadIdx.x >> 6);   // wave id = output id
  const int lane = threadIdx.x & 63;
  const int b = w / NOUT;
  const int t = w - b * NOUT;

  int v = 0x7fffffff;
  if (lane < WIN_MED) {
    int j = t + lane - 14;               // left replicate-pad by 14
    if (j < 0) j = 0;
    v = best[b * KFRAMES + j];
  }
  int c_lt = 0, c_le = 0;
  #pragma unroll
  for (int j = 0; j < WIN_MED; ++j) {
    int bv = __shfl(v, j, 64);
    c_lt += (bv < v) ? 1 : 0;
    c_le += (bv <= v) ? 1 : 0;
  }
  // lower median = sorted[14]: value with count(<v) <= 14 < count(<=v)
  bool cond = (lane < WIN_MED) && (c_lt <= 14) && (c_le > 14);
  unsigned long long m = __ballot(cond);
  int sel = __ffsll((long long)m) - 1;
  int med = __shfl(v, sel, 64);
  if (lane == 0) {
    float f0 = 16000.0f / (1e-9f + (float)med);
    out[b * NOUT + t] = f0;              // f0
    out[2 * NTOT + b * NOUT + t] = 1.0f; // voiced (f0 > 0 always)
  }
}

// ---------------- Kernel 3: whiten (single block: reduce + apply) ----------------
__global__ __launch_bounds__(256) void whiten_kernel(float* __restrict__ out) {
  __shared__ double red[256];
  __shared__ double red2[256];
  const int t = threadIdx.x;
  double s = 0.0, s2 = 0.0;
  for (int i = t; i < NTOT; i += 256) {
    double f = (double)out[i];
    s += f; s2 += f * f;
  }
  red[t] = s; red2[t] = s2;
  __syncthreads();
  for (int st = 128; st > 0; st >>= 1) {
    if (t < st) { red[t] += red[t + st]; red2[t] += red2[t + st]; }
    __syncthreads();
  }
  __shared__ float fmean_s, finvsd_s;
  if (t == 0) {
    const double n = (double)NTOT;
    double mean = red[0] / n;
    double var = (red2[0] - n * mean * mean) / (n - 1.0);
    if (var < 0.0) var = 0.0;
    double sd = sqrt(var);
    fmean_s = (float)mean;
    finvsd_s = (sd == 0.0) ? 1.0f : (float)(1.0 / sd);
  }
  __syncthreads();
  float fmean = fmean_s, finvsd = finvsd_s;
  for (int i = t; i < NTOT; i += 256) {
    out[NTOT + i] = (out[i] - fmean) * finvsd;
  }
}

extern "C" void kernel_launch(void* const* d_in, const int* in_sizes, int n_in,
                              void* d_out, int out_size, void* d_ws, size_t ws_size,
                              hipStream_t stream) {
  const float* audio = (const float*)d_in[0];
  float* out = (float*)d_out;
  int* best = (int*)d_ws;   // 2000 ints

  dim3 g1(KFRAMES, BATCH);
  nccf_best_kernel<<<g1, 64, 0, stream>>>(audio, best, out);
  median_f0_kernel<<<(NTOT + 3) / 4, 256, 0, stream>>>(best, out);
  whiten_kernel<<<1, 256, 0, stream>>>(out);
}